// Round 3
// baseline (960.049 us; speedup 1.0000x reference)
//
#include <hip/hip_runtime.h>
#include <hip/hip_bf16.h>
#include <math.h>

#define Bb 2
#define Tt 2048
#define Dd 1024
#define Hh 16
#define DKk 64

typedef __bf16 bf16_t;
typedef __bf16 bf16x8 __attribute__((ext_vector_type(8)));
typedef __bf16 bf16x4 __attribute__((ext_vector_type(4)));
typedef float f32x4 __attribute__((ext_vector_type(4)));

// async global->LDS, 16B per lane. LDS dest = wave-uniform base + lane*16.
__device__ __forceinline__ void async16(const void* gsrc, void* ldst) {
  void* g = const_cast<void*>(gsrc);
  __builtin_amdgcn_global_load_lds(
      (__attribute__((address_space(1))) void*)g,
      (__attribute__((address_space(3))) void*)ldst, 16, 0, 0);
}

__device__ __forceinline__ bf16x8 cvt8(const float4 a, const float4 b) {
  bf16x8 o;
  o[0] = (bf16_t)a.x; o[1] = (bf16_t)a.y; o[2] = (bf16_t)a.z; o[3] = (bf16_t)a.w;
  o[4] = (bf16_t)b.x; o[5] = (bf16_t)b.y; o[6] = (bf16_t)b.z; o[7] = (bf16_t)b.w;
  return o;
}

// ---------------- GEMM: C[M,N] = A[M,K] @ B[N,K]^T + bias ----------------
// A, Bw, bias fp32; C bf16. Converts to bf16 during LDS staging.
#define BM 128
#define BN 128
#define BK 64

__global__ __launch_bounds__(256) void gemm_f32_bt_bias(
    const float* __restrict__ A, const float* __restrict__ Bw,
    const float* __restrict__ bias, bf16_t* __restrict__ C,
    int M, int N, int K) {
  __shared__ bf16_t As[BM * BK];
  __shared__ bf16_t Bs[BN * BK];
  const int tid = threadIdx.x;
  const int lane = tid & 63;
  const int w = tid >> 6;
  const int wy = w >> 1, wx = w & 1;
  const int m0 = blockIdx.y * BM, n0 = blockIdx.x * BN;
  const int q = lane >> 4, cc = lane & 15;
  const int srow = lane >> 3;          // 0..7 within 8-row slab
  const int scol = (lane & 7) * 8;     // elem offset in row

  f32x4 acc[4][4] = {};

  for (int k0 = 0; k0 < K; k0 += BK) {
    __syncthreads();
#pragma unroll
    for (int i = 0; i < 4; ++i) {
      const int row = (w * 4 + i) * 8 + srow;  // wave w covers rows w*32..w*32+31
      const float* ap = A + (size_t)(m0 + row) * K + k0 + scol;
      const float* bp = Bw + (size_t)(n0 + row) * K + k0 + scol;
      *(bf16x8*)(As + row * BK + scol) =
          cvt8(*(const float4*)ap, *(const float4*)(ap + 4));
      *(bf16x8*)(Bs + row * BK + scol) =
          cvt8(*(const float4*)bp, *(const float4*)(bp + 4));
    }
    __syncthreads();
#pragma unroll
    for (int kk = 0; kk < 2; ++kk) {
      bf16x8 af[4], bfr[4];
#pragma unroll
      for (int i = 0; i < 4; ++i)
        af[i] = *(const bf16x8*)(As + (wy * 64 + i * 16 + cc) * BK + kk * 32 + q * 8);
#pragma unroll
      for (int j = 0; j < 4; ++j)
        bfr[j] = *(const bf16x8*)(Bs + (wx * 64 + j * 16 + cc) * BK + kk * 32 + q * 8);
#pragma unroll
      for (int i = 0; i < 4; ++i)
#pragma unroll
        for (int j = 0; j < 4; ++j)
          acc[i][j] = __builtin_amdgcn_mfma_f32_16x16x32_bf16(af[i], bfr[j], acc[i][j], 0, 0, 0);
    }
  }

#pragma unroll
  for (int j = 0; j < 4; ++j) {
    const int col = n0 + wx * 64 + j * 16 + cc;
    const float bv = bias[col];
#pragma unroll
    for (int i = 0; i < 4; ++i) {
      const int row = m0 + wy * 64 + i * 16 + q * 4;
#pragma unroll
      for (int r = 0; r < 4; ++r)
        C[(size_t)(row + r) * N + col] = (bf16_t)(acc[i][j][r] + bv);
    }
  }
}

// ---------------- fused attention ----------------
// grid (T/64, H, B), 256 thr. 2-pass: pass1 = online (max,sum) per row;
// pass2 = recompute S, P = exp(s-m)/(1+l), write attn (fp32), X = P@V (fp32 out).
__global__ __launch_bounds__(256) void attn_fused(
    const bf16_t* __restrict__ Qm, const bf16_t* __restrict__ Km,
    const bf16_t* __restrict__ Vm,
    float* __restrict__ attn_out,   // [B,H,T,T] fp32
    float* __restrict__ X) {        // [B,T,D] fp32
  __shared__ bf16_t Qs[64 * 64];
  __shared__ bf16_t Ks[64 * 64];
  __shared__ bf16_t Vt[64 * 64];  // transposed: Vt[d][k]
  __shared__ bf16_t Ps[64 * 64];

  const int tid = threadIdx.x;
  const int lane = tid & 63;
  const int w = tid >> 6;
  const int qt = blockIdx.x, h = blockIdx.y, b = blockIdx.z;
  const int q = lane >> 4, cc = lane & 15;
  const size_t base = (size_t)b * Tt * Dd + (size_t)h * DKk;
  const int srow = lane >> 3;
  const int scol = (lane & 7) * 8;
  const float scale = 0.125f;  // 1/sqrt(64)

  // stage Q tile (64 rows x 64 cols); drained by first __syncthreads below
  for (int i = 0; i < 2; ++i) {
    const int r0 = (w * 2 + i) * 8;
    async16(Qm + base + (size_t)(qt * 64 + r0 + srow) * Dd + scol, Qs + r0 * 64);
  }

  float Mr[4], Lr[4];
#pragma unroll
  for (int r = 0; r < 4; ++r) { Mr[r] = -3.0e38f; Lr[r] = 0.f; }

  // ---- pass 1 ----
  for (int kt = 0; kt < 32; ++kt) {
    __syncthreads();
    for (int i = 0; i < 2; ++i) {
      const int r0 = (w * 2 + i) * 8;
      async16(Km + base + (size_t)(kt * 64 + r0 + srow) * Dd + scol, Ks + r0 * 64);
    }
    __syncthreads();
    f32x4 acc[4] = {};
#pragma unroll
    for (int kk = 0; kk < 2; ++kk) {
      const bf16x8 af = *(const bf16x8*)(Qs + (w * 16 + cc) * 64 + kk * 32 + q * 8);
#pragma unroll
      for (int j = 0; j < 4; ++j) {
        const bf16x8 bfr = *(const bf16x8*)(Ks + (j * 16 + cc) * 64 + kk * 32 + q * 8);
        acc[j] = __builtin_amdgcn_mfma_f32_16x16x32_bf16(af, bfr, acc[j], 0, 0, 0);
      }
    }
#pragma unroll
    for (int r = 0; r < 4; ++r) {
      float mx = fmaxf(fmaxf(acc[0][r], acc[1][r]), fmaxf(acc[2][r], acc[3][r])) * scale;
#pragma unroll
      for (int msk = 1; msk < 16; msk <<= 1) mx = fmaxf(mx, __shfl_xor(mx, msk));
      const float mnew = fmaxf(Mr[r], mx);
      float sum = 0.f;
#pragma unroll
      for (int j = 0; j < 4; ++j) sum += __expf(acc[j][r] * scale - mnew);
#pragma unroll
      for (int msk = 1; msk < 16; msk <<= 1) sum += __shfl_xor(sum, msk);
      Lr[r] = Lr[r] * __expf(Mr[r] - mnew) + sum;
      Mr[r] = mnew;
    }
  }

  float inv1pl[4];
#pragma unroll
  for (int r = 0; r < 4; ++r) inv1pl[r] = 1.f / (1.f + Lr[r]);

  f32x4 xacc[4] = {};
  const size_t arowbase = ((size_t)(b * Hh + h) * Tt + (size_t)qt * 64) * Tt;

  // ---- pass 2 ----
  for (int kt = 0; kt < 32; ++kt) {
    __syncthreads();
    for (int i = 0; i < 2; ++i) {
      const int r0 = (w * 2 + i) * 8;
      async16(Km + base + (size_t)(kt * 64 + r0 + srow) * Dd + scol, Ks + r0 * 64);
    }
    // stage V transposed (scalar LDS writes)
    for (int i = 0; i < 2; ++i) {
      const int chunk = tid * 2 + i;  // 0..511
      const int vr = chunk >> 3;      // k index 0..63
      const int vc = (chunk & 7) * 8; // d base
      const bf16x8 vv = *(const bf16x8*)(Vm + base + (size_t)(kt * 64 + vr) * Dd + vc);
#pragma unroll
      for (int e = 0; e < 8; ++e) Vt[(vc + e) * 64 + vr] = vv[e];
    }
    __syncthreads();
    f32x4 acc[4] = {};
#pragma unroll
    for (int kk = 0; kk < 2; ++kk) {
      const bf16x8 af = *(const bf16x8*)(Qs + (w * 16 + cc) * 64 + kk * 32 + q * 8);
#pragma unroll
      for (int j = 0; j < 4; ++j) {
        const bf16x8 bfr = *(const bf16x8*)(Ks + (j * 16 + cc) * 64 + kk * 32 + q * 8);
        acc[j] = __builtin_amdgcn_mfma_f32_16x16x32_bf16(af, bfr, acc[j], 0, 0, 0);
      }
    }
    // P: fp32 store to attn_out (C-layout addressing) + bf16 into Ps for PV
#pragma unroll
    for (int j = 0; j < 4; ++j)
#pragma unroll
      for (int r = 0; r < 4; ++r) {
        const float p = __expf(acc[j][r] * scale - Mr[r]) * inv1pl[r];
        const int prow = w * 16 + q * 4 + r;
        const int pcol = j * 16 + cc;
        attn_out[arowbase + (size_t)prow * Tt + kt * 64 + pcol] = p;
        Ps[prow * 64 + pcol] = (bf16_t)p;
      }
    __syncthreads();
    // PV
#pragma unroll
    for (int kk = 0; kk < 2; ++kk) {
      const bf16x8 af = *(const bf16x8*)(Ps + (w * 16 + cc) * 64 + kk * 32 + q * 8);
#pragma unroll
      for (int j = 0; j < 4; ++j) {
        const bf16x8 bfr = *(const bf16x8*)(Vt + (j * 16 + cc) * 64 + kk * 32 + q * 8);
        xacc[j] = __builtin_amdgcn_mfma_f32_16x16x32_bf16(af, bfr, xacc[j], 0, 0, 0);
      }
    }
  }

#pragma unroll
  for (int j = 0; j < 4; ++j)
#pragma unroll
    for (int r = 0; r < 4; ++r) {
      const int row = qt * 64 + w * 16 + q * 4 + r;
      X[base + (size_t)row * Dd + j * 16 + cc] = xacc[j][r];
    }
}

// ---------------- residual + LayerNorm (fp32 out) ----------------
__global__ __launch_bounds__(256) void ln_kernel(
    const float* __restrict__ resid, const bf16_t* __restrict__ O,
    const float* __restrict__ gamma, const float* __restrict__ beta,
    float* __restrict__ out) {
  const int row = blockIdx.x;
  const int tid = threadIdx.x;
  const size_t roff = (size_t)row * Dd + tid * 4;
  const float4 rv = *(const float4*)(resid + roff);
  const bf16x4 ov = *(const bf16x4*)(O + roff);
  const float y0 = rv.x + (float)ov.x;
  const float y1 = rv.y + (float)ov.y;
  const float y2 = rv.z + (float)ov.z;
  const float y3 = rv.w + (float)ov.w;
  float s = y0 + y1 + y2 + y3;
  float s2 = y0 * y0 + y1 * y1 + y2 * y2 + y3 * y3;
#pragma unroll
  for (int msk = 1; msk < 64; msk <<= 1) {
    s += __shfl_xor(s, msk);
    s2 += __shfl_xor(s2, msk);
  }
  __shared__ float red[8];
  const int w = tid >> 6;
  if ((tid & 63) == 0) { red[w] = s; red[4 + w] = s2; }
  __syncthreads();
  s = red[0] + red[1] + red[2] + red[3];
  s2 = red[4] + red[5] + red[6] + red[7];
  const float mu = s * (1.f / Dd);
  const float rstd = rsqrtf(s2 * (1.f / Dd) - mu * mu + 1e-5f);
  const float4 gv = *(const float4*)(gamma + tid * 4);
  const float4 bv = *(const float4*)(beta + tid * 4);
  float4 o;
  o.x = (y0 - mu) * rstd * gv.x + bv.x;
  o.y = (y1 - mu) * rstd * gv.y + bv.y;
  o.z = (y2 - mu) * rstd * gv.z + bv.z;
  o.w = (y3 - mu) * rstd * gv.w + bv.w;
  *(float4*)(out + roff) = o;
}

extern "C" void kernel_launch(void* const* d_in, const int* in_sizes, int n_in,
                              void* d_out, int out_size, void* d_ws, size_t ws_size,
                              hipStream_t stream) {
  const float* query = (const float*)d_in[0];
  const float* key = (const float*)d_in[1];
  const float* value = (const float*)d_in[2];
  const float* Wq = (const float*)d_in[3];
  const float* bq = (const float*)d_in[4];
  const float* Wk = (const float*)d_in[5];
  const float* bk = (const float*)d_in[6];
  const float* Wv = (const float*)d_in[7];
  const float* bv = (const float*)d_in[8];
  const float* Wo = (const float*)d_in[9];
  const float* bo = (const float*)d_in[10];
  const float* gamma = (const float*)d_in[11];
  const float* beta = (const float*)d_in[12];

  float* y_out = (float*)d_out;                       // [B,T,D] fp32
  float* attn_out = y_out + (size_t)Bb * Tt * Dd;     // [B,H,T,T] fp32

  // workspace: 3x bf16 [B,T,D] (8MB) + fp32 X (16MB) + bf16 O (8MB) = 48MB
  char* p = (char*)d_ws;
  const size_t nTD = (size_t)Bb * Tt * Dd;  // 4,194,304
  bf16_t* Qb = (bf16_t*)p;  p += nTD * 2;
  bf16_t* Kb = (bf16_t*)p;  p += nTD * 2;
  bf16_t* Vb = (bf16_t*)p;  p += nTD * 2;
  float*  Xf = (float*)p;   p += nTD * 4;
  bf16_t* Ob = (bf16_t*)p;  p += nTD * 2;

  dim3 gg(Dd / BN, (Bb * Tt) / BM);  // (8, 32)
  gemm_f32_bt_bias<<<gg, 256, 0, stream>>>(query, Wq, bq, Qb, Bb * Tt, Dd, Dd);
  gemm_f32_bt_bias<<<gg, 256, 0, stream>>>(key, Wk, bk, Kb, Bb * Tt, Dd, Dd);
  gemm_f32_bt_bias<<<gg, 256, 0, stream>>>(value, Wv, bv, Vb, Bb * Tt, Dd, Dd);

  dim3 ga(Tt / 64, Hh, Bb);  // (32, 16, 2)
  attn_fused<<<ga, 256, 0, stream>>>(Qb, Kb, Vb, attn_out, Xf);

  gemm_f32_bt_bias<<<gg, 256, 0, stream>>>(Xf, Wo, bo, Ob, Bb * Tt, Dd, Dd);

  ln_kernel<<<Bb * Tt, 256, 0, stream>>>(query, Ob, gamma, beta, y_out);
}